// Round 5
// baseline (402.833 us; speedup 1.0000x reference)
//
#include <hip/hip_runtime.h>

// Stochastic LIF neuron scan, fp32, shapes B=32, T=16, N=65536.
//   u = 0.5*u + x[t]; u -= noise[t];
//   p = clip((u - 1.0 + 0.4)/0.8, 0, 1); o = (unif[t] < p); u *= (1-o)
// Memory-bound: ~335-512 MB HBM traffic (L3 absorbs part of reads).
//
// R1: 166us rolled loop, vmcnt(0) stall each t (3 KB/wave in flight).
// R2: 154us, 2 scans/thread pipelined -- grid halved -> 38% occupancy,
//     VALUBusy 11%, 2.2 TB/s: concurrency-bound.
// R3..R5: 1 scan/thread (2048 blocks -> 32 waves/CU possible) + prefetch
//     t+1 (3 KB/wave always in flight) + nontemporal stores (no-reuse
//     output stream must not evict L3-resident inputs).
//     R3 compile fix: __builtin_nontemporal_store needs clang native
//     vector -> ext_vector_type(4). R4 compile fix: can't bind float& to
//     a vector element -> copy lane to local float, write back.

namespace {

typedef float f32x4 __attribute__((ext_vector_type(4)));

constexpr int B = 32;
constexpr int T = 16;
constexpr int N = 65536;
constexpr int N4 = N / 4;            // 16384 f32x4 per (b,t) row
constexpr int N4_SHIFT = 14;         // log2(N4)

constexpr float SIGMA = 0.4f;        // A
constexpr float TWO_SIGMA = 0.8f;    // 2*A
constexpr float THRESHOLD = 1.0f;
constexpr float TAU_INV = 0.5f;

// One timestep, one scalar element. Must match reference fp32 op order:
// mul+add (0.5*u exact, fma-safe), sub, sub, add, IEEE divide (do NOT
// fold to *1.25f), clamp, compare, mul.
__device__ __forceinline__ float lif_step(float& u, float xi, float ni, float ri) {
    u = TAU_INV * u + xi;            // leaky integrate
    u = u - ni;                      // noise injection
    float v = u - THRESHOLD;
    float p = (v + SIGMA) / TWO_SIGMA;  // IEEE fp32 divide
    p = fminf(fmaxf(p, 0.0f), 1.0f);
    float o = (ri < p) ? 1.0f : 0.0f;
    u = u * (1.0f - o);              // hard reset where spiked
    return o;
}

__device__ __forceinline__ f32x4 lif_step4(f32x4& u, const f32x4 xi,
                                           const f32x4 ni, const f32x4 ri) {
    f32x4 o;
    float ux = u.x, uy = u.y, uz = u.z, uw = u.w;   // vector elems can't bind to float&
    o.x = lif_step(ux, xi.x, ni.x, ri.x);
    o.y = lif_step(uy, xi.y, ni.y, ri.y);
    o.z = lif_step(uz, xi.z, ni.z, ri.z);
    o.w = lif_step(uw, xi.w, ni.w, ri.w);
    u.x = ux; u.y = uy; u.z = uz; u.w = uw;
    return o;
}

__global__ __launch_bounds__(256) void snn_scan_kernel(
    const f32x4* __restrict__ x,
    const f32x4* __restrict__ noise,
    const f32x4* __restrict__ unif,
    f32x4* __restrict__ out)
{
    const int tid = blockIdx.x * blockDim.x + threadIdx.x;   // [0, B * N4)
    const int b  = tid >> N4_SHIFT;
    const int nc = tid & (N4 - 1);

    int idx = b * T * N4 + nc;       // f32x4 index of (b, t=0, nc)
    f32x4 u = {0.f, 0.f, 0.f, 0.f};

    // prologue: load t=0
    f32x4 cx = x[idx], cn = noise[idx], cr = unif[idx];

    for (int t = 0; t < T - 1; ++t) {
        const int nidx = idx + N4;
        // issue t+1 loads before computing t: 3 KB/wave stays in flight
        // across the compute+store phase
        f32x4 nx = x[nidx], nn = noise[nidx], nr = unif[nidx];

        f32x4 o = lif_step4(u, cx, cn, cr);
        __builtin_nontemporal_store(o, &out[idx]);   // no-reuse stream: keep out of L3

        cx = nx; cn = nn; cr = nr;
        idx = nidx;
    }

    // epilogue: last timestep
    f32x4 o = lif_step4(u, cx, cn, cr);
    __builtin_nontemporal_store(o, &out[idx]);
}

} // namespace

extern "C" void kernel_launch(void* const* d_in, const int* in_sizes, int n_in,
                              void* d_out, int out_size, void* d_ws, size_t ws_size,
                              hipStream_t stream) {
    const f32x4* x     = (const f32x4*)d_in[0];
    const f32x4* noise = (const f32x4*)d_in[1];
    const f32x4* unif  = (const f32x4*)d_in[2];
    f32x4* out         = (f32x4*)d_out;

    const int threads_total = B * N4;            // 524288 (1 scan/thread)
    const int block = 256;
    const int grid = threads_total / block;      // 2048 blocks, 8/CU -> 32 waves/CU

    snn_scan_kernel<<<grid, block, 0, stream>>>(x, noise, unif, out);
}